// Round 12
// baseline (10544.563 us; speedup 1.0000x reference)
//
#include <hip/hip_runtime.h>
#include <hip/hip_bf16.h>
#include <math.h>

#define BB 64
#define NN 2048
#define HID 64
#define NLAYERS 4
#define CGS 5

// ws layout in floats
#define WS_X      0                      // 2*BB*NN
#define WS_FEATS  (2*BB*NN)              // 2*BB*NN
#define WS_CS     (4*BB*NN)              // 2*BB*NN
#define WS_HEFF   (6*BB*NN)              // 2*BB*NN
#define WS_HH     (8*BB*NN)              // BB*NN
#define WS_LAM    (9*BB*NN)              // BB
#define WS_GPN    (9*BB*NN + BB)
#define WS_GNL    (9*BB*NN + 2*BB)
#define WS_GGR    (9*BB*NN + 3*BB)
#define WS_REL    (9*BB*NN + 4*BB)       // NLAYERS accumulators
#define WS_RNN    (9*BB*NN + 4*BB + 64)  // fp32 region: BB*NN*128 floats

typedef float v2f __attribute__((ext_vector_type(2)));

__device__ __forceinline__ float sigf(float x) { return 1.0f / (1.0f + expf(-x)); }
__device__ __forceinline__ float softplusf(float x) {
    return fmaxf(x, 0.0f) + log1pf(expf(-fabsf(x)));
}
// fast activations for the GRU inner loop (v_exp_f32 / v_rcp_f32 based, ~1e-6 rel err)
__device__ __forceinline__ float fsig(float x) {
    return __builtin_amdgcn_rcpf(1.0f + __expf(-x));
}
__device__ __forceinline__ float ftanh(float x) {
    float ax = fabsf(x);
    float e = __expf(-2.0f * ax);
    float t = (1.0f - e) * __builtin_amdgcn_rcpf(1.0f + e);
    return copysignf(t, x);
}

// ---------------- K0: per-batch scalars (reg/lam, gPN, gNL, ggrad) ----------
__global__ __launch_bounds__(64) void k_scalars(
    const float* __restrict__ gamma, const float* __restrict__ meta,
    const float* __restrict__ rw1, const float* __restrict__ rb1,
    const float* __restrict__ rw2, const float* __restrict__ rb2,
    const float* __restrict__ pw1, const float* __restrict__ pb1,
    const float* __restrict__ lng, const float* __restrict__ lnb,
    const float* __restrict__ pw2, const float* __restrict__ pb2,
    const float* __restrict__ pw3, const float* __restrict__ pb3,
    float* __restrict__ ws)
{
    int b = threadIdx.x;
    if (b < NLAYERS) ws[WS_REL + b] = 0.0f;
    if (b >= BB) return;

    float g = gamma[b];
    float acc = rb2[0];
    for (int j = 0; j < 16; j++) {
        float t = fmaxf(fmaf(g, rw1[j], rb1[j]), 0.0f);
        acc = fmaf(t, rw2[j], acc);
    }
    float lam = softplusf(acc) + 1e-6f;
    float log_vol = -logf(lam) * 3.0f;

    float m[6];
    for (int i = 0; i < 6; i++) m[i] = meta[b * 6 + i];
    float h1[64];
    float mu = 0.0f;
    for (int j = 0; j < 64; j++) {
        float a = pb1[j];
        for (int i = 0; i < 6; i++) a = fmaf(m[i], pw1[j * 6 + i], a);
        h1[j] = a; mu += a;
    }
    mu *= (1.0f / 64.0f);
    float var = 0.0f;
    for (int j = 0; j < 64; j++) { float d = h1[j] - mu; var = fmaf(d, d, var); }
    var *= (1.0f / 64.0f);
    float inv = 1.0f / sqrtf(var + 1e-5f);
    for (int j = 0; j < 64; j++) h1[j] = (h1[j] - mu) * inv * lng[j] + lnb[j];

    float h2[32];
    for (int k = 0; k < 32; k++) {
        float a = pb2[k];
        for (int j = 0; j < 64; j++) {
            float r = fmaxf(h1[j], 0.0f);
            a = fmaf(r, pw2[k * 64 + j], a);
        }
        h2[k] = fmaxf(a, 0.0f);
    }
    float lg[3];
    for (int o = 0; o < 3; o++) {
        float a = pb3[o];
        for (int k = 0; k < 32; k++) a = fmaf(h2[k], pw3[o * 32 + k], a);
        lg[o] = a;
    }
    float gPN = sigf(lg[0]);
    float gNL = softplusf(lg[1]) + 0.5f;
    float brake = sigf((log_vol + 15.0f) * 5.0f);
    float ggr = sigf(lg[2]) * brake;

    ws[WS_LAM + b] = lam;
    ws[WS_GPN + b] = gPN;
    ws[WS_GNL + b] = gNL;
    ws[WS_GGR + b] = ggr;
}

// ---------------- K0b: channel (double-precision phase) + zero x_est --------
__global__ __launch_bounds__(256) void k_chan(
    const float* __restrict__ theta, const float* __restrict__ bg,
    float* __restrict__ ws)
{
    int idx = blockIdx.x * 256 + threadIdx.x;   // b*NN + n
    int b = idx >> 11;
    int n = idx & (NN - 1);
    double th0 = (double)theta[b * 3 + 0];
    double th1 = (double)theta[b * 3 + 1];
    double th2 = (double)theta[b * 3 + 2];
    const double Cc = 300000000.0, FS = 10000000000.0, FC = 300000000000.0;
    double tau = th0 / Cc, td = th1 / Cc, tdd = th2 / Cc;
    double t = (double)n / FS;
    double phase = 6.283185307179586 * FC * (tau + td * t + 0.5 * tdd * t * t);
    double s, c;
    sincos(phase, &s, &c);
    float gain = bg[0];
    float hr = (float)c * gain;
    float hi = (float)(-s) * gain;
    ws[WS_HEFF + 2 * idx] = hr;
    ws[WS_HEFF + 2 * idx + 1] = hi;
    ws[WS_HH + idx] = hr * hr + hi * hi;
    ws[WS_X + 2 * idx] = 0.0f;
    ws[WS_X + 2 * idx + 1] = 0.0f;
}

// ---------------- K1: feats (reliable-select + resid) -----------------------
__global__ __launch_bounds__(256) void k_feats(
    const float* __restrict__ yr, const float* __restrict__ yi,
    float* __restrict__ ws, int layer)
{
    float rel = ws[WS_REL + layer] * (1.0f / (BB * NN));
    bool reliable = rel > 0.1f;
    int idx = blockIdx.x * 256 + threadIdx.x;
    float Yr = yr[idx], Yi = yi[idx];
    float fr, fi;
    if (reliable) {
        float xr = ws[WS_X + 2 * idx], xi = ws[WS_X + 2 * idx + 1];
        float a = sqrtf(xr * xr + xi * xi) + 1e-6f;
        float nr = xr / a, ni = xi / a;
        fr = Yr * nr + Yi * ni;
        fi = Yi * nr - Yr * ni;
    } else {
        fr = Yr; fi = Yi;
    }
    ws[WS_FEATS + 2 * idx] = fr;
    ws[WS_FEATS + 2 * idx + 1] = fi;
}

// ---------------- K2: GRU, ONE WAVE, TWO CHAINS (same direction) ------------
// R6's barrier-free single-wave skeleton, but each wave advances TWO chains
// (two batches, same direction => same weights). Rationale (R6-R11 data):
// per-step cost = issue(~300-600) + dependency-stall(~300-600) in every
// structure; the stall is LDS round-trip + transcendental latency. Two
// independent recurrences on one wave let chain B's issue fill chain A's
// stalls, and the (non-resident) weight reload stream — the dominant issue
// cost — is SHARED: each loaded weight feeds 2 pk-FMAs.
__global__ __attribute__((amdgpu_flat_work_group_size(64, 64), amdgpu_waves_per_eu(1, 1)))
void k_gru(
    const float* __restrict__ feats,
    const float* __restrict__ wih_f, const float* __restrict__ whh_f,
    const float* __restrict__ bih_f, const float* __restrict__ bhh_f,
    const float* __restrict__ wih_b, const float* __restrict__ whh_b,
    const float* __restrict__ bih_b, const float* __restrict__ bhh_b,
    float* __restrict__ rnn)
{
    __shared__ float sfA[2 * NN], sfB[2 * NN];       // 32 KB feats (2 chains)
    __shared__ __align__(16) float shA[HID], shB[HID];

    int bp = blockIdx.x;          // 64 blocks
    int d = bp & 1;
    int p = bp >> 1;              // pair index 0..31
    int b0 = 2 * p, b1 = 2 * p + 1;
    int lane = threadIdx.x;

    const float* wih = d ? wih_b : wih_f;
    const float* whh = d ? whh_b : whh_f;
    const float* bih = d ? bih_b : bih_f;
    const float* bhh = d ? bhh_b : bhh_f;

    // per-lane gate weights: rows lane, 64+lane, 128+lane (shared by chains)
    v2f WR[32], WZ[32], WN[32];
    {
        const float4* rr = reinterpret_cast<const float4*>(whh + (size_t)lane * 64);
        const float4* rz = reinterpret_cast<const float4*>(whh + (size_t)(64 + lane) * 64);
        const float4* rn = reinterpret_cast<const float4*>(whh + (size_t)(128 + lane) * 64);
        #pragma unroll
        for (int q = 0; q < 16; q++) {
            float4 v = rr[q]; WR[2 * q] = (v2f){v.x, v.y}; WR[2 * q + 1] = (v2f){v.z, v.w};
            float4 w = rz[q]; WZ[2 * q] = (v2f){w.x, w.y}; WZ[2 * q + 1] = (v2f){w.z, w.w};
            float4 u = rn[q]; WN[2 * q] = (v2f){u.x, u.y}; WN[2 * q + 1] = (v2f){u.z, u.w};
        }
    }
    float wir0 = wih[lane * 2],            wir1 = wih[lane * 2 + 1];
    float wiz0 = wih[(64 + lane) * 2],     wiz1 = wih[(64 + lane) * 2 + 1];
    float win0 = wih[(128 + lane) * 2],    win1 = wih[(128 + lane) * 2 + 1];
    float bir = bih[lane], biz = bih[64 + lane], bin = bih[128 + lane];
    float bhr = bhh[lane], bhz = bhh[64 + lane], bhn = bhh[128 + lane];

    // stage both chains' feats to LDS (float4, coalesced)
    {
        const float4* fpA = reinterpret_cast<const float4*>(feats + (size_t)b0 * 2 * NN);
        const float4* fpB = reinterpret_cast<const float4*>(feats + (size_t)b1 * 2 * NN);
        float4* spA = reinterpret_cast<float4*>(sfA);
        float4* spB = reinterpret_cast<float4*>(sfB);
        for (int j = lane; j < NN / 2; j += 64) { spA[j] = fpA[j]; spB[j] = fpB[j]; }
    }
    float hA = 0.0f, hB = 0.0f;
    shA[lane] = 0.0f;
    shB[lane] = 0.0f;
    __syncthreads();   // single wave: trivial

    const float2* fptrA = reinterpret_cast<const float2*>(sfA) + (d ? (NN - 1) : 0);
    const float2* fptrB = reinterpret_cast<const float2*>(sfB) + (d ? (NN - 1) : 0);
    int fstep = d ? -1 : 1;
    size_t o0 = (size_t)(d ? (NN - 1) : 0) * 128 + d * 64 + lane;
    float* optrA = rnn + (size_t)b0 * NN * 128 + o0;
    float* optrB = rnn + (size_t)b1 * NN * 128 + o0;
    ptrdiff_t ostep = d ? -128 : 128;

    #pragma unroll 2
    for (int s = 0; s < NN; s++) {
        float2 fA = *fptrA; fptrA += fstep;        // broadcast LDS reads
        float2 fB = *fptrB; fptrB += fstep;
        float xprA = fmaf(fA.y, wir1, fmaf(fA.x, wir0, bir));
        float xpzA = fmaf(fA.y, wiz1, fmaf(fA.x, wiz0, biz));
        float xpnA = fmaf(fA.y, win1, fmaf(fA.x, win0, bin));
        float xprB = fmaf(fB.y, wir1, fmaf(fB.x, wir0, bir));
        float xpzB = fmaf(fB.y, wiz1, fmaf(fB.x, wiz0, biz));
        float xpnB = fmaf(fB.y, win1, fmaf(fB.x, win0, bin));

        v2f arA0 = {0,0}, arA1 = {0,0}, azA0 = {0,0}, azA1 = {0,0}, anA0 = {0,0}, anA1 = {0,0};
        v2f arB0 = {0,0}, arB1 = {0,0}, azB0 = {0,0}, azB1 = {0,0}, anB0 = {0,0}, anB1 = {0,0};
        #pragma unroll
        for (int q = 0; q < 16; q++) {
            float4 hvA = *reinterpret_cast<const float4*>(&shA[4 * q]);  // broadcast
            float4 hvB = *reinterpret_cast<const float4*>(&shB[4 * q]);
            v2f hA01 = {hvA.x, hvA.y}, hA23 = {hvA.z, hvA.w};
            v2f hB01 = {hvB.x, hvB.y}, hB23 = {hvB.z, hvB.w};
            v2f wr0 = WR[2 * q], wr1 = WR[2 * q + 1];   // weight loaded once,
            v2f wz0 = WZ[2 * q], wz1 = WZ[2 * q + 1];   // used by both chains
            v2f wn0 = WN[2 * q], wn1 = WN[2 * q + 1];
            arA0 = __builtin_elementwise_fma(wr0, hA01, arA0);
            arB0 = __builtin_elementwise_fma(wr0, hB01, arB0);
            arA1 = __builtin_elementwise_fma(wr1, hA23, arA1);
            arB1 = __builtin_elementwise_fma(wr1, hB23, arB1);
            azA0 = __builtin_elementwise_fma(wz0, hA01, azA0);
            azB0 = __builtin_elementwise_fma(wz0, hB01, azB0);
            azA1 = __builtin_elementwise_fma(wz1, hA23, azA1);
            azB1 = __builtin_elementwise_fma(wz1, hB23, azB1);
            anA0 = __builtin_elementwise_fma(wn0, hA01, anA0);
            anB0 = __builtin_elementwise_fma(wn0, hB01, anB0);
            anA1 = __builtin_elementwise_fma(wn1, hA23, anA1);
            anB1 = __builtin_elementwise_fma(wn1, hB23, anB1);
        }
        v2f arsA = arA0 + arA1, azsA = azA0 + azA1, ansA = anA0 + anA1;
        v2f arsB = arB0 + arB1, azsB = azB0 + azB1, ansB = anB0 + anB1;
        float ghrA = bhr + (arsA.x + arsA.y);
        float ghzA = bhz + (azsA.x + azsA.y);
        float ghnA = bhn + (ansA.x + ansA.y);
        float ghrB = bhr + (arsB.x + arsB.y);
        float ghzB = bhz + (azsB.x + azsB.y);
        float ghnB = bhn + (ansB.x + ansB.y);

        float rA = fsig(xprA + ghrA);
        float rB = fsig(xprB + ghrB);
        float zA = fsig(xpzA + ghzA);
        float zB = fsig(xpzB + ghzB);
        float nA = ftanh(fmaf(rA, ghnA, xpnA));
        float nB = ftanh(fmaf(rB, ghnB, xpnB));
        hA = (1.0f - zA) * nA + zA * hA;
        hB = (1.0f - zB) * nB + zB * hB;

        shA[lane] = hA;                       // ds_writes; next iter's reads
        shB[lane] = hB;                       // are lgkmcnt-ordered (same wave)
        *optrA = hA; optrA += ostep;          // coalesced 256B stores, no wait
        *optrB = hB; optrB += ostep;
    }
}

// ---------------- K3: head 128 -> 32(relu) -> 2 -----------------------------
__global__ __launch_bounds__(256) void k_head(
    const float* __restrict__ rnn,
    const float* __restrict__ hw1, const float* __restrict__ hb1,
    const float* __restrict__ hw2, const float* __restrict__ hb2,
    float* __restrict__ cs)
{
    __shared__ float sw1[32 * 128];
    __shared__ float sb1[32], sw2[64], sb2[2];
    int tid = threadIdx.x;
    for (int i = tid; i < 4096; i += 256) sw1[i] = hw1[i];
    if (tid < 32) sb1[tid] = hb1[tid];
    if (tid < 64) sw2[tid] = hw2[tid];
    if (tid < 2)  sb2[tid] = hb2[tid];
    __syncthreads();

    int idx = blockIdx.x * 256 + tid;     // b*NN + t
    float x[128];
    const float4* rp = reinterpret_cast<const float4*>(rnn + (size_t)idx * 128);
    #pragma unroll
    for (int q = 0; q < 32; q++) {
        float4 v = rp[q];
        x[q * 4 + 0] = v.x;
        x[q * 4 + 1] = v.y;
        x[q * 4 + 2] = v.z;
        x[q * 4 + 3] = v.w;
    }

    float c0 = sb2[0], c1 = sb2[1];
    for (int k = 0; k < 32; k++) {
        float a = sb1[k];
        #pragma unroll
        for (int j = 0; j < 128; j++) a = fmaf(x[j], sw1[k * 128 + j], a);
        a = fmaxf(a, 0.0f);
        c0 = fmaf(a, sw2[k], c0);
        c1 = fmaf(a, sw2[32 + k], c1);
    }
    cs[2 * idx] = c0;
    cs[2 * idx + 1] = c1;
}

// ---------------- K4: derot/tanh/onsager/CG/update, one block per row -------
__device__ __forceinline__ float block_sum(float v, float* sred, int tid) {
    #pragma unroll
    for (int o = 32; o > 0; o >>= 1) v += __shfl_down(v, o, 64);
    __syncthreads();
    if ((tid & 63) == 0) sred[tid >> 6] = v;
    __syncthreads();
    return sred[0] + sred[1] + sred[2] + sred[3];
}

__global__ __launch_bounds__(256) void k_solve(
    const float* __restrict__ yr, const float* __restrict__ yi,
    float* __restrict__ ws,
    const float* __restrict__ scale_slope, const float* __restrict__ phase_bias,
    float* __restrict__ out, int layer)
{
    __shared__ float sred[4];
    int b = blockIdx.x, tid = threadIdx.x;
    float lam = ws[WS_LAM + b], gPN = ws[WS_GPN + b];
    float gNL = ws[WS_GNL + b], gg = ws[WS_GGR + b];
    float beta = scale_slope[0] * gNL;
    float pb = phase_bias[0];
    float bsr = cosf(pb), bsi = -sinf(pb);

    float Yr[8], Yi[8], Hr[8], Hi[8], dA[8], Xr[8], Xi[8], Br[8], Bi[8];
    float ons = 0.0f;
    #pragma unroll
    for (int i = 0; i < 8; i++) {
        int idx = b * NN + tid + i * 256;
        float yr_ = yr[idx], yi_ = yi[idx];
        float c = ws[WS_CS + 2 * idx], s = ws[WS_CS + 2 * idx + 1];
        float mag = sqrtf(c * c + s * s + 1e-8f);
        float dr = c / mag, di = -s / mag;
        float der = dr * bsr - di * bsi;
        float dei = dr * bsi + di * bsr;
        float er = 1.0f - gPN + gPN * der;
        float ei = gPN * dei;
        float ea = sqrtf(er * er + ei * ei) + 1e-8f;
        er /= ea; ei /= ea;
        float zri = yr_ * er - yi_ * ei;
        float zii = yr_ * ei + yi_ * er;
        float zr = tanhf(beta * zri);
        float zi = tanhf(beta * zii);
        ons += beta * (1.0f - zr * zr) + beta * (1.0f - zi * zi);
        Yr[i] = yr_; Yi[i] = yi_;
        Hr[i] = ws[WS_HEFF + 2 * idx]; Hi[i] = ws[WS_HEFF + 2 * idx + 1];
        dA[i] = ws[WS_HH + idx] + lam;
        Xr[i] = ws[WS_X + 2 * idx]; Xi[i] = ws[WS_X + 2 * idx + 1];
        Br[i] = zr; Bi[i] = zi;   // holds z_out for now
    }
    float onsager = block_sum(ons, sred, tid) * (0.5f / NN);

    #pragma unroll
    for (int i = 0; i < 8; i++) {
        float zcr = Br[i] - onsager * Xr[i];
        float zci = Bi[i] - onsager * Xi[i];
        Br[i] = Hr[i] * zcr + Hi[i] * zci;    // conj(h) * z_corr
        Bi[i] = Hr[i] * zci - Hi[i] * zcr;
    }

    float xr[8], xi[8], Rr[8], Ri[8], Pr[8], Pi[8];
    float rs_p = 0.0f;
    #pragma unroll
    for (int i = 0; i < 8; i++) {
        xr[i] = Xr[i]; xi[i] = Xi[i];
        Rr[i] = Br[i] - dA[i] * xr[i];
        Ri[i] = Bi[i] - dA[i] * xi[i];
        Pr[i] = Rr[i]; Pi[i] = Ri[i];
        rs_p += Rr[i] * Rr[i] + Ri[i] * Ri[i];
    }
    float rs = block_sum(rs_p, sred, tid);

    for (int it = 0; it < CGS; it++) {
        float pap = 0.0f;
        #pragma unroll
        for (int i = 0; i < 8; i++) pap += dA[i] * (Pr[i] * Pr[i] + Pi[i] * Pi[i]);
        float alpha = rs / (block_sum(pap, sred, tid) + 1e-20f);
        float rsn_p = 0.0f;
        #pragma unroll
        for (int i = 0; i < 8; i++) {
            xr[i] += alpha * Pr[i]; xi[i] += alpha * Pi[i];
            Rr[i] -= alpha * dA[i] * Pr[i];
            Ri[i] -= alpha * dA[i] * Pi[i];
            rsn_p += Rr[i] * Rr[i] + Ri[i] * Ri[i];
        }
        float rsn = block_sum(rsn_p, sred, tid);
        float bsc = rsn / (rs + 1e-20f);
        #pragma unroll
        for (int i = 0; i < 8; i++) {
            Pr[i] = Rr[i] + bsc * Pr[i];
            Pi[i] = Ri[i] + bsc * Pi[i];
        }
        rs = rsn;
    }

    float relp = 0.0f;
    float* dstx = (layer == NLAYERS - 1) ? out : (ws + WS_X);
    #pragma unroll
    for (int i = 0; i < 8; i++) {
        int idx = b * NN + tid + i * 256;
        float nr = (1.0f - gg) * Xr[i] + gg * xr[i];
        float ni = (1.0f - gg) * Xi[i] + gg * xi[i];
        dstx[2 * idx] = nr;
        dstx[2 * idx + 1] = ni;
        if (layer < NLAYERS - 1) {
            ws[WS_X + 2 * idx] = nr;
            ws[WS_X + 2 * idx + 1] = ni;
        }
        relp += sqrtf(nr * nr + ni * ni);
    }
    float relsum = block_sum(relp, sred, tid);
    if (tid == 0 && layer + 1 < NLAYERS) atomicAdd(ws + WS_REL + layer + 1, relsum);
}

// ---------------- launch ----------------------------------------------------
extern "C" void kernel_launch(void* const* d_in, const int* in_sizes, int n_in,
                              void* d_out, int out_size, void* d_ws, size_t ws_size,
                              hipStream_t stream)
{
    const float* yr    = (const float*)d_in[0];
    const float* yi    = (const float*)d_in[1];
    const float* theta = (const float*)d_in[2];
    const float* meta  = (const float*)d_in[3];
    const float* gamma = (const float*)d_in[4];
    const float* sslope= (const float*)d_in[5];
    const float* bgain = (const float*)d_in[6];
    const float* rw1   = (const float*)d_in[7];
    const float* rb1   = (const float*)d_in[8];
    const float* rw2   = (const float*)d_in[9];
    const float* rb2   = (const float*)d_in[10];
    const float* pw1   = (const float*)d_in[11];
    const float* pb1   = (const float*)d_in[12];
    const float* lng   = (const float*)d_in[13];
    const float* lnb   = (const float*)d_in[14];
    const float* pw2   = (const float*)d_in[15];
    const float* pb2   = (const float*)d_in[16];
    const float* pw3   = (const float*)d_in[17];
    const float* pb3   = (const float*)d_in[18];
    const float* wih_f = (const float*)d_in[19];
    const float* whh_f = (const float*)d_in[20];
    const float* bih_f = (const float*)d_in[21];
    const float* bhh_f = (const float*)d_in[22];
    const float* wih_b = (const float*)d_in[23];
    const float* whh_b = (const float*)d_in[24];
    const float* bih_b = (const float*)d_in[25];
    const float* bhh_b = (const float*)d_in[26];
    const float* hw1   = (const float*)d_in[27];
    const float* hb1   = (const float*)d_in[28];
    const float* hw2   = (const float*)d_in[29];
    const float* hb2   = (const float*)d_in[30];
    const float* pbias = (const float*)d_in[31];

    float* ws = (float*)d_ws;
    float* out = (float*)d_out;
    float* rnn = ws + WS_RNN;

    k_scalars<<<1, 64, 0, stream>>>(gamma, meta, rw1, rb1, rw2, rb2,
                                    pw1, pb1, lng, lnb, pw2, pb2, pw3, pb3, ws);
    k_chan<<<(BB * NN) / 256, 256, 0, stream>>>(theta, bgain, ws);

    for (int L = 0; L < NLAYERS; L++) {
        k_feats<<<(BB * NN) / 256, 256, 0, stream>>>(yr, yi, ws, L);
        k_gru<<<64, 64, 0, stream>>>(ws + WS_FEATS,
                                     wih_f, whh_f, bih_f, bhh_f,
                                     wih_b, whh_b, bih_b, bhh_b, rnn);
        k_head<<<(BB * NN) / 256, 256, 0, stream>>>(rnn, hw1, hb1, hw2, hb2,
                                                    ws + WS_CS);
        k_solve<<<BB, 256, 0, stream>>>(yr, yi, ws, sslope, pbias, out, L);
    }
}

// Round 13
// 3164.515 us; speedup vs baseline: 3.3321x; 3.3321x over previous
//
#include <hip/hip_runtime.h>
#include <hip/hip_bf16.h>
#include <math.h>

#define BB 64
#define NN 2048
#define HID 64
#define NLAYERS 4
#define CGS 5

// ws layout in floats
#define WS_X      0                      // 2*BB*NN
#define WS_FEATS  (2*BB*NN)              // 2*BB*NN
#define WS_CS     (4*BB*NN)              // 2*BB*NN
#define WS_HEFF   (6*BB*NN)              // 2*BB*NN
#define WS_HH     (8*BB*NN)              // BB*NN
#define WS_LAM    (9*BB*NN)              // BB
#define WS_GPN    (9*BB*NN + BB)
#define WS_GNL    (9*BB*NN + 2*BB)
#define WS_GGR    (9*BB*NN + 3*BB)
#define WS_REL    (9*BB*NN + 4*BB)       // NLAYERS accumulators
#define WS_RNN    (9*BB*NN + 4*BB + 64)  // fp32 region: BB*NN*128 floats

typedef float v2f __attribute__((ext_vector_type(2)));

__device__ __forceinline__ float sigf(float x) { return 1.0f / (1.0f + expf(-x)); }
__device__ __forceinline__ float softplusf(float x) {
    return fmaxf(x, 0.0f) + log1pf(expf(-fabsf(x)));
}
// fast activations for the GRU inner loop (v_exp_f32 / v_rcp_f32 based, ~1e-6 rel err)
__device__ __forceinline__ float fsig(float x) {
    return __builtin_amdgcn_rcpf(1.0f + __expf(-x));
}
__device__ __forceinline__ float ftanh(float x) {
    float ax = fabsf(x);
    float e = __expf(-2.0f * ax);
    float t = (1.0f - e) * __builtin_amdgcn_rcpf(1.0f + e);
    return copysignf(t, x);
}

// ---------------- K0: per-batch scalars (reg/lam, gPN, gNL, ggrad) ----------
__global__ __launch_bounds__(64) void k_scalars(
    const float* __restrict__ gamma, const float* __restrict__ meta,
    const float* __restrict__ rw1, const float* __restrict__ rb1,
    const float* __restrict__ rw2, const float* __restrict__ rb2,
    const float* __restrict__ pw1, const float* __restrict__ pb1,
    const float* __restrict__ lng, const float* __restrict__ lnb,
    const float* __restrict__ pw2, const float* __restrict__ pb2,
    const float* __restrict__ pw3, const float* __restrict__ pb3,
    float* __restrict__ ws)
{
    int b = threadIdx.x;
    if (b < NLAYERS) ws[WS_REL + b] = 0.0f;
    if (b >= BB) return;

    float g = gamma[b];
    float acc = rb2[0];
    for (int j = 0; j < 16; j++) {
        float t = fmaxf(fmaf(g, rw1[j], rb1[j]), 0.0f);
        acc = fmaf(t, rw2[j], acc);
    }
    float lam = softplusf(acc) + 1e-6f;
    float log_vol = -logf(lam) * 3.0f;

    float m[6];
    for (int i = 0; i < 6; i++) m[i] = meta[b * 6 + i];
    float h1[64];
    float mu = 0.0f;
    for (int j = 0; j < 64; j++) {
        float a = pb1[j];
        for (int i = 0; i < 6; i++) a = fmaf(m[i], pw1[j * 6 + i], a);
        h1[j] = a; mu += a;
    }
    mu *= (1.0f / 64.0f);
    float var = 0.0f;
    for (int j = 0; j < 64; j++) { float d = h1[j] - mu; var = fmaf(d, d, var); }
    var *= (1.0f / 64.0f);
    float inv = 1.0f / sqrtf(var + 1e-5f);
    for (int j = 0; j < 64; j++) h1[j] = (h1[j] - mu) * inv * lng[j] + lnb[j];

    float h2[32];
    for (int k = 0; k < 32; k++) {
        float a = pb2[k];
        for (int j = 0; j < 64; j++) {
            float r = fmaxf(h1[j], 0.0f);
            a = fmaf(r, pw2[k * 64 + j], a);
        }
        h2[k] = fmaxf(a, 0.0f);
    }
    float lg[3];
    for (int o = 0; o < 3; o++) {
        float a = pb3[o];
        for (int k = 0; k < 32; k++) a = fmaf(h2[k], pw3[o * 32 + k], a);
        lg[o] = a;
    }
    float gPN = sigf(lg[0]);
    float gNL = softplusf(lg[1]) + 0.5f;
    float brake = sigf((log_vol + 15.0f) * 5.0f);
    float ggr = sigf(lg[2]) * brake;

    ws[WS_LAM + b] = lam;
    ws[WS_GPN + b] = gPN;
    ws[WS_GNL + b] = gNL;
    ws[WS_GGR + b] = ggr;
}

// ---------------- K0b: channel (double-precision phase) + zero x_est --------
__global__ __launch_bounds__(256) void k_chan(
    const float* __restrict__ theta, const float* __restrict__ bg,
    float* __restrict__ ws)
{
    int idx = blockIdx.x * 256 + threadIdx.x;   // b*NN + n
    int b = idx >> 11;
    int n = idx & (NN - 1);
    double th0 = (double)theta[b * 3 + 0];
    double th1 = (double)theta[b * 3 + 1];
    double th2 = (double)theta[b * 3 + 2];
    const double Cc = 300000000.0, FS = 10000000000.0, FC = 300000000000.0;
    double tau = th0 / Cc, td = th1 / Cc, tdd = th2 / Cc;
    double t = (double)n / FS;
    double phase = 6.283185307179586 * FC * (tau + td * t + 0.5 * tdd * t * t);
    double s, c;
    sincos(phase, &s, &c);
    float gain = bg[0];
    float hr = (float)c * gain;
    float hi = (float)(-s) * gain;
    ws[WS_HEFF + 2 * idx] = hr;
    ws[WS_HEFF + 2 * idx + 1] = hi;
    ws[WS_HH + idx] = hr * hr + hi * hi;
    ws[WS_X + 2 * idx] = 0.0f;
    ws[WS_X + 2 * idx + 1] = 0.0f;
}

// ---------------- K1: feats (reliable-select + resid) -----------------------
__global__ __launch_bounds__(256) void k_feats(
    const float* __restrict__ yr, const float* __restrict__ yi,
    float* __restrict__ ws, int layer)
{
    float rel = ws[WS_REL + layer] * (1.0f / (BB * NN));
    bool reliable = rel > 0.1f;
    int idx = blockIdx.x * 256 + threadIdx.x;
    float Yr = yr[idx], Yi = yi[idx];
    float fr, fi;
    if (reliable) {
        float xr = ws[WS_X + 2 * idx], xi = ws[WS_X + 2 * idx + 1];
        float a = sqrtf(xr * xr + xi * xi) + 1e-6f;
        float nr = xr / a, ni = xi / a;
        fr = Yr * nr + Yi * ni;
        fi = Yi * nr - Yr * ni;
    } else {
        fr = Yr; fi = Yi;
    }
    ws[WS_FEATS + 2 * idx] = fr;
    ws[WS_FEATS + 2 * idx + 1] = fi;
}

// ---------------- K2: GRU, 4 waves per chain, k-split (R8 base) -------------
// Best-measured structure (790us/dispatch). Wave w owns k-slice [16w,16w+16)
// of ALL THREE gate matvecs: 48 weight floats/lane (24 v2f). R8 shipped with
// VGPR_Count=48 => weights were re-streamed each step; waves_per_eu(1,1)
// (4 waves = 1/EU for a 256-thread block anyway) lifts the allocator budget
// so the 24 pairs can stay arch-VGPR-resident. Per step: 24 pk-FMA, 3 b32
// partial writes, ONE raw s_barrier (lgkmcnt-only — no vmcnt drain of the
// per-step global store), 12 conflict-free gather reads, redundant gates in
// all waves. h quarters self-written/self-read per wave -> no 2nd barrier.
// P double-buffered; unroll 2 const-folds the buffer index.
__global__ __attribute__((amdgpu_flat_work_group_size(256, 256), amdgpu_waves_per_eu(1, 1)))
void k_gru(
    const float* __restrict__ feats,
    const float* __restrict__ wih_f, const float* __restrict__ whh_f,
    const float* __restrict__ bih_f, const float* __restrict__ bhh_f,
    const float* __restrict__ wih_b, const float* __restrict__ whh_b,
    const float* __restrict__ bih_b, const float* __restrict__ bhh_b,
    float* __restrict__ rnn)
{
    __shared__ float sf[2 * NN];                     // 16 KB feats
    __shared__ __align__(16) float shq[4][16];       // per-wave h quarter
    __shared__ float P[2][3][4][64];                 // [buf][gate][wave][lane]

    int chain = blockIdx.x;
    int b = chain >> 1;
    int d = chain & 1;
    int tid = threadIdx.x;
    int lane = tid & 63;
    int w = tid >> 6;

    const float* wih = d ? wih_b : wih_f;
    const float* whh = d ? whh_b : whh_f;
    const float* bih = d ? bih_b : bih_f;
    const float* bhh = d ? bhh_b : bhh_f;

    // wave w, lane i: whh rows {i, 64+i, 128+i}, cols [16w, 16w+16)
    v2f WR[8], WZ[8], WN[8];
    {
        const float4* rr = reinterpret_cast<const float4*>(whh + (size_t)lane * 64 + 16 * w);
        const float4* rz = reinterpret_cast<const float4*>(whh + (size_t)(64 + lane) * 64 + 16 * w);
        const float4* rn = reinterpret_cast<const float4*>(whh + (size_t)(128 + lane) * 64 + 16 * w);
        #pragma unroll
        for (int q = 0; q < 4; q++) {
            float4 v = rr[q]; WR[2 * q] = (v2f){v.x, v.y}; WR[2 * q + 1] = (v2f){v.z, v.w};
            float4 u = rz[q]; WZ[2 * q] = (v2f){u.x, u.y}; WZ[2 * q + 1] = (v2f){u.z, u.w};
            float4 x = rn[q]; WN[2 * q] = (v2f){x.x, x.y}; WN[2 * q + 1] = (v2f){x.z, x.w};
        }
    }
    float wir0 = wih[lane * 2],            wir1 = wih[lane * 2 + 1];
    float wiz0 = wih[(64 + lane) * 2],     wiz1 = wih[(64 + lane) * 2 + 1];
    float win0 = wih[(128 + lane) * 2],    win1 = wih[(128 + lane) * 2 + 1];
    float bir = bih[lane], biz = bih[64 + lane], bin = bih[128 + lane];
    float bhr = bhh[lane], bhz = bhh[64 + lane], bhn = bhh[128 + lane];

    // stage feats to LDS (float4, coalesced, 256 threads)
    {
        const float4* fp = reinterpret_cast<const float4*>(feats + (size_t)b * 2 * NN);
        float4* sp = reinterpret_cast<float4*>(sf);
        for (int j = tid; j < NN / 2; j += 256) sp[j] = fp[j];
    }
    float h = 0.0f;
    if ((lane >> 4) == w) shq[w][lane & 15] = 0.0f;
    __syncthreads();   // once, before the loop (staging + init visible)

    const float2* fptr = reinterpret_cast<const float2*>(sf) + (d ? (NN - 1) : 0);
    int fstep = d ? -1 : 1;
    float* optr = rnn + (size_t)b * NN * 128 + (size_t)(d ? (NN - 1) : 0) * 128
                + d * 64 + lane;
    ptrdiff_t ostep = d ? -128 : 128;

    #pragma unroll 2
    for (int s = 0; s < NN; s++) {
        int pb = s & 1;                           // const-folded by unroll 2
        float2 f = *fptr;                         // broadcast LDS read
        fptr += fstep;
        float xpr = fmaf(f.y, wir1, fmaf(f.x, wir0, bir));
        float xpz = fmaf(f.y, wiz1, fmaf(f.x, wiz0, biz));
        float xpn = fmaf(f.y, win1, fmaf(f.x, win0, bin));

        // partial matvecs over this wave's k-slice (24 pk-FMA)
        v2f ar0 = {0, 0}, ar1 = {0, 0}, az0 = {0, 0}, az1 = {0, 0},
            an0 = {0, 0}, an1 = {0, 0};
        #pragma unroll
        for (int q = 0; q < 4; q++) {
            float4 hv = *reinterpret_cast<const float4*>(&shq[w][4 * q]);  // broadcast
            v2f h01 = {hv.x, hv.y};
            v2f h23 = {hv.z, hv.w};
            ar0 = __builtin_elementwise_fma(WR[2 * q],     h01, ar0);
            ar1 = __builtin_elementwise_fma(WR[2 * q + 1], h23, ar1);
            az0 = __builtin_elementwise_fma(WZ[2 * q],     h01, az0);
            az1 = __builtin_elementwise_fma(WZ[2 * q + 1], h23, az1);
            an0 = __builtin_elementwise_fma(WN[2 * q],     h01, an0);
            an1 = __builtin_elementwise_fma(WN[2 * q + 1], h23, an1);
        }
        v2f ars = ar0 + ar1, azs = az0 + az1, ans = an0 + an1;
        P[pb][0][w][lane] = ars.x + ars.y;
        P[pb][1][w][lane] = azs.x + azs.y;
        P[pb][2][w][lane] = ans.x + ans.y;

        asm volatile("s_waitcnt lgkmcnt(0)" ::: "memory");  // partials visible
        __builtin_amdgcn_s_barrier();                       // no vmcnt drain
        asm volatile("" ::: "memory");

        // gather (conflict-free: bank = lane%32, 2-way)
        float ghr = bhr + ((P[pb][0][0][lane] + P[pb][0][1][lane]) +
                           (P[pb][0][2][lane] + P[pb][0][3][lane]));
        float ghz = bhz + ((P[pb][1][0][lane] + P[pb][1][1][lane]) +
                           (P[pb][1][2][lane] + P[pb][1][3][lane]));
        float ghn = bhn + ((P[pb][2][0][lane] + P[pb][2][1][lane]) +
                           (P[pb][2][2][lane] + P[pb][2][3][lane]));

        float r = fsig(xpr + ghr);
        float z = fsig(xpz + ghz);
        float n = ftanh(fmaf(r, ghn, xpn));
        h = (1.0f - z) * n + z * h;               // identical in all 4 waves

        if ((lane >> 4) == w) shq[w][lane & 15] = h;   // own quarter only
        if (w == 0) *optr = h;                    // coalesced 256B store
        optr += ostep;
    }
}

// ---------------- K3: head 128 -> 32(relu) -> 2 -----------------------------
__global__ __launch_bounds__(256) void k_head(
    const float* __restrict__ rnn,
    const float* __restrict__ hw1, const float* __restrict__ hb1,
    const float* __restrict__ hw2, const float* __restrict__ hb2,
    float* __restrict__ cs)
{
    __shared__ float sw1[32 * 128];
    __shared__ float sb1[32], sw2[64], sb2[2];
    int tid = threadIdx.x;
    for (int i = tid; i < 4096; i += 256) sw1[i] = hw1[i];
    if (tid < 32) sb1[tid] = hb1[tid];
    if (tid < 64) sw2[tid] = hw2[tid];
    if (tid < 2)  sb2[tid] = hb2[tid];
    __syncthreads();

    int idx = blockIdx.x * 256 + tid;     // b*NN + t
    float x[128];
    const float4* rp = reinterpret_cast<const float4*>(rnn + (size_t)idx * 128);
    #pragma unroll
    for (int q = 0; q < 32; q++) {
        float4 v = rp[q];
        x[q * 4 + 0] = v.x;
        x[q * 4 + 1] = v.y;
        x[q * 4 + 2] = v.z;
        x[q * 4 + 3] = v.w;
    }

    float c0 = sb2[0], c1 = sb2[1];
    for (int k = 0; k < 32; k++) {
        float a = sb1[k];
        #pragma unroll
        for (int j = 0; j < 128; j++) a = fmaf(x[j], sw1[k * 128 + j], a);
        a = fmaxf(a, 0.0f);
        c0 = fmaf(a, sw2[k], c0);
        c1 = fmaf(a, sw2[32 + k], c1);
    }
    cs[2 * idx] = c0;
    cs[2 * idx + 1] = c1;
}

// ---------------- K4: derot/tanh/onsager/CG/update, one block per row -------
__device__ __forceinline__ float block_sum(float v, float* sred, int tid) {
    #pragma unroll
    for (int o = 32; o > 0; o >>= 1) v += __shfl_down(v, o, 64);
    __syncthreads();
    if ((tid & 63) == 0) sred[tid >> 6] = v;
    __syncthreads();
    return sred[0] + sred[1] + sred[2] + sred[3];
}

__global__ __launch_bounds__(256) void k_solve(
    const float* __restrict__ yr, const float* __restrict__ yi,
    float* __restrict__ ws,
    const float* __restrict__ scale_slope, const float* __restrict__ phase_bias,
    float* __restrict__ out, int layer)
{
    __shared__ float sred[4];
    int b = blockIdx.x, tid = threadIdx.x;
    float lam = ws[WS_LAM + b], gPN = ws[WS_GPN + b];
    float gNL = ws[WS_GNL + b], gg = ws[WS_GGR + b];
    float beta = scale_slope[0] * gNL;
    float pb = phase_bias[0];
    float bsr = cosf(pb), bsi = -sinf(pb);

    float Yr[8], Yi[8], Hr[8], Hi[8], dA[8], Xr[8], Xi[8], Br[8], Bi[8];
    float ons = 0.0f;
    #pragma unroll
    for (int i = 0; i < 8; i++) {
        int idx = b * NN + tid + i * 256;
        float yr_ = yr[idx], yi_ = yi[idx];
        float c = ws[WS_CS + 2 * idx], s = ws[WS_CS + 2 * idx + 1];
        float mag = sqrtf(c * c + s * s + 1e-8f);
        float dr = c / mag, di = -s / mag;
        float der = dr * bsr - di * bsi;
        float dei = dr * bsi + di * bsr;
        float er = 1.0f - gPN + gPN * der;
        float ei = gPN * dei;
        float ea = sqrtf(er * er + ei * ei) + 1e-8f;
        er /= ea; ei /= ea;
        float zri = yr_ * er - yi_ * ei;
        float zii = yr_ * ei + yi_ * er;
        float zr = tanhf(beta * zri);
        float zi = tanhf(beta * zii);
        ons += beta * (1.0f - zr * zr) + beta * (1.0f - zi * zi);
        Yr[i] = yr_; Yi[i] = yi_;
        Hr[i] = ws[WS_HEFF + 2 * idx]; Hi[i] = ws[WS_HEFF + 2 * idx + 1];
        dA[i] = ws[WS_HH + idx] + lam;
        Xr[i] = ws[WS_X + 2 * idx]; Xi[i] = ws[WS_X + 2 * idx + 1];
        Br[i] = zr; Bi[i] = zi;   // holds z_out for now
    }
    float onsager = block_sum(ons, sred, tid) * (0.5f / NN);

    #pragma unroll
    for (int i = 0; i < 8; i++) {
        float zcr = Br[i] - onsager * Xr[i];
        float zci = Bi[i] - onsager * Xi[i];
        Br[i] = Hr[i] * zcr + Hi[i] * zci;    // conj(h) * z_corr
        Bi[i] = Hr[i] * zci - Hi[i] * zcr;
    }

    float xr[8], xi[8], Rr[8], Ri[8], Pr[8], Pi[8];
    float rs_p = 0.0f;
    #pragma unroll
    for (int i = 0; i < 8; i++) {
        xr[i] = Xr[i]; xi[i] = Xi[i];
        Rr[i] = Br[i] - dA[i] * xr[i];
        Ri[i] = Bi[i] - dA[i] * xi[i];
        Pr[i] = Rr[i]; Pi[i] = Ri[i];
        rs_p += Rr[i] * Rr[i] + Ri[i] * Ri[i];
    }
    float rs = block_sum(rs_p, sred, tid);

    for (int it = 0; it < CGS; it++) {
        float pap = 0.0f;
        #pragma unroll
        for (int i = 0; i < 8; i++) pap += dA[i] * (Pr[i] * Pr[i] + Pi[i] * Pi[i]);
        float alpha = rs / (block_sum(pap, sred, tid) + 1e-20f);
        float rsn_p = 0.0f;
        #pragma unroll
        for (int i = 0; i < 8; i++) {
            xr[i] += alpha * Pr[i]; xi[i] += alpha * Pi[i];
            Rr[i] -= alpha * dA[i] * Pr[i];
            Ri[i] -= alpha * dA[i] * Pi[i];
            rsn_p += Rr[i] * Rr[i] + Ri[i] * Ri[i];
        }
        float rsn = block_sum(rsn_p, sred, tid);
        float bsc = rsn / (rs + 1e-20f);
        #pragma unroll
        for (int i = 0; i < 8; i++) {
            Pr[i] = Rr[i] + bsc * Pr[i];
            Pi[i] = Ri[i] + bsc * Pi[i];
        }
        rs = rsn;
    }

    float relp = 0.0f;
    float* dstx = (layer == NLAYERS - 1) ? out : (ws + WS_X);
    #pragma unroll
    for (int i = 0; i < 8; i++) {
        int idx = b * NN + tid + i * 256;
        float nr = (1.0f - gg) * Xr[i] + gg * xr[i];
        float ni = (1.0f - gg) * Xi[i] + gg * xi[i];
        dstx[2 * idx] = nr;
        dstx[2 * idx + 1] = ni;
        if (layer < NLAYERS - 1) {
            ws[WS_X + 2 * idx] = nr;
            ws[WS_X + 2 * idx + 1] = ni;
        }
        relp += sqrtf(nr * nr + ni * ni);
    }
    float relsum = block_sum(relp, sred, tid);
    if (tid == 0 && layer + 1 < NLAYERS) atomicAdd(ws + WS_REL + layer + 1, relsum);
}

// ---------------- launch ----------------------------------------------------
extern "C" void kernel_launch(void* const* d_in, const int* in_sizes, int n_in,
                              void* d_out, int out_size, void* d_ws, size_t ws_size,
                              hipStream_t stream)
{
    const float* yr    = (const float*)d_in[0];
    const float* yi    = (const float*)d_in[1];
    const float* theta = (const float*)d_in[2];
    const float* meta  = (const float*)d_in[3];
    const float* gamma = (const float*)d_in[4];
    const float* sslope= (const float*)d_in[5];
    const float* bgain = (const float*)d_in[6];
    const float* rw1   = (const float*)d_in[7];
    const float* rb1   = (const float*)d_in[8];
    const float* rw2   = (const float*)d_in[9];
    const float* rb2   = (const float*)d_in[10];
    const float* pw1   = (const float*)d_in[11];
    const float* pb1   = (const float*)d_in[12];
    const float* lng   = (const float*)d_in[13];
    const float* lnb   = (const float*)d_in[14];
    const float* pw2   = (const float*)d_in[15];
    const float* pb2   = (const float*)d_in[16];
    const float* pw3   = (const float*)d_in[17];
    const float* pb3   = (const float*)d_in[18];
    const float* wih_f = (const float*)d_in[19];
    const float* whh_f = (const float*)d_in[20];
    const float* bih_f = (const float*)d_in[21];
    const float* bhh_f = (const float*)d_in[22];
    const float* wih_b = (const float*)d_in[23];
    const float* whh_b = (const float*)d_in[24];
    const float* bih_b = (const float*)d_in[25];
    const float* bhh_b = (const float*)d_in[26];
    const float* hw1   = (const float*)d_in[27];
    const float* hb1   = (const float*)d_in[28];
    const float* hw2   = (const float*)d_in[29];
    const float* hb2   = (const float*)d_in[30];
    const float* pbias = (const float*)d_in[31];

    float* ws = (float*)d_ws;
    float* out = (float*)d_out;
    float* rnn = ws + WS_RNN;

    k_scalars<<<1, 64, 0, stream>>>(gamma, meta, rw1, rb1, rw2, rb2,
                                    pw1, pb1, lng, lnb, pw2, pb2, pw3, pb3, ws);
    k_chan<<<(BB * NN) / 256, 256, 0, stream>>>(theta, bgain, ws);

    for (int L = 0; L < NLAYERS; L++) {
        k_feats<<<(BB * NN) / 256, 256, 0, stream>>>(yr, yi, ws, L);
        k_gru<<<BB * 2, 256, 0, stream>>>(ws + WS_FEATS,
                                          wih_f, whh_f, bih_f, bhh_f,
                                          wih_b, whh_b, bih_b, bhh_b, rnn);
        k_head<<<(BB * NN) / 256, 256, 0, stream>>>(rnn, hw1, hb1, hw2, hb2,
                                                    ws + WS_CS);
        k_solve<<<BB, 256, 0, stream>>>(yr, yi, ws, sslope, pbias, out, L);
    }
}